// Round 1
// 2044.464 us; speedup vs baseline: 2.8469x; 2.8469x over previous
//
#include <hip/hip_runtime.h>

// Problem constants
#define NB 32
#define LL 1024
#define HH 768
#define RR (NB * LL)          // 32768 rows
#define PE_C (-0.01199263069f) // -ln(10000)/768

typedef unsigned short u16;
typedef float f32x4 __attribute__((ext_vector_type(4)));
typedef u16   u16x8 __attribute__((ext_vector_type(8)));
typedef __bf16 bf16x8 __attribute__((ext_vector_type(8)));

// ---------------------------------------------------------------------------
// block-wide reduce of two sums (blockDim.x must be 256)
__device__ __forceinline__ float2 block_reduce2(float a, float b) {
    __shared__ float sa[4], sb[4];
    #pragma unroll
    for (int off = 32; off; off >>= 1) {
        a += __shfl_down(a, off, 64);
        b += __shfl_down(b, off, 64);
    }
    int lane = threadIdx.x & 63, wid = threadIdx.x >> 6;
    __syncthreads();                 // protect sa/sb from a previous call
    if (lane == 0) { sa[wid] = a; sb[wid] = b; }
    __syncthreads();
    a = (sa[0] + sa[1]) + (sa[2] + sa[3]);
    b = (sb[0] + sb[1]) + (sb[2] + sb[3]);
    return make_float2(a, b);
}

// ---------------------------------------------------------------------------
// Per-row mean / rstd over D columns. If ids != nullptr, row r is X[ids[r]].
__global__ __launch_bounds__(256) void row_stats(
    const float* __restrict__ X, const int* __restrict__ ids, int D,
    float* __restrict__ stats)
{
    int r = blockIdx.x;
    const float* row = X + (ids ? (long)ids[r] * D : (long)r * D);
    float s = 0.f, ss = 0.f;
    for (int c = threadIdx.x * 4; c < D; c += 1024) {
        float4 v = *(const float4*)(row + c);
        s  += (v.x + v.y) + (v.z + v.w);
        ss += (v.x * v.x + v.y * v.y) + (v.z * v.z + v.w * v.w);
    }
    float2 t = block_reduce2(s, ss);
    if (threadIdx.x == 0) {
        float mean = t.x / D;
        float var  = fmaxf(t.y / D - mean * mean, 0.f);
        stats[2 * r]     = mean;
        stats[2 * r + 1] = 1.f / sqrtf(var + 1e-12f);
    }
}

// ---------------------------------------------------------------------------
// Fold LN1's affine into W and bias, split W' = g1*W into bf16 hi/lo planes
// (zero-padded to Kpad), and bias2[n] = bias[n] + sum_k b1[k]*W[n][k].
// One block per output row n (768 blocks x 256 threads).
__global__ __launch_bounds__(256) void prep_w(
    const float* __restrict__ W, const float* __restrict__ bias,
    const float* __restrict__ g1, const float* __restrict__ b1,
    int K, int Kpad,
    u16* __restrict__ Whi, u16* __restrict__ Wlo, float* __restrict__ bias2)
{
    const int n = blockIdx.x;
    const float* wr = W + (long)n * K;
    float s = 0.f;
    for (int k = threadIdx.x; k < Kpad; k += 256) {
        float v = 0.f;
        if (k < K) {
            float w = wr[k];
            s += b1[k] * w;
            v  = g1[k] * w;
        }
        unsigned u  = __float_as_uint(v);
        unsigned hb = u & 0xffff0000u;
        float    lo = v - __uint_as_float(hb);
        Whi[(long)n * Kpad + k] = (u16)(u >> 16);
        Wlo[(long)n * Kpad + k] = (u16)(__float_as_uint(lo) >> 16);
    }
    float2 t = block_reduce2(s, 0.f);
    if (threadIdx.x == 0) bias2[n] = bias[n] + t.x;
}

// ---------------------------------------------------------------------------
// Y[m][n] = ReLU( sum_k xn[m][k] * W'[n][k] + bias2[n] ), xn = (x-mean)*rstd.
// bf16x3 split-precision MFMA (fp32-equivalent): acc += Alo*Bhi + Ahi*Blo
// + Ahi*Bhi. Tile 128x128, BK=32, 4 waves of 4x4 16x16x32 fragments.
// LDS rows padded to 40 bf16 (80B stride -> conflict-free b128 frag reads).
__global__ __launch_bounds__(256, 2) void gemm_mfma(
    const float* __restrict__ A, const int* __restrict__ ids,
    const int K, const int Kpad,
    const u16* __restrict__ Whi, const u16* __restrict__ Wlo,
    const float* __restrict__ bias2, const float* __restrict__ stats,
    float* __restrict__ Y)
{
    __shared__ u16 Ah[128][40];
    __shared__ u16 Al[128][40];
    __shared__ u16 Bh[128][40];
    __shared__ u16 Bl[128][40];

    // XCD-bijective swizzle (gridDim.x = 1536, divisible by 8); n fastest so
    // the 6 blocks sharing one A-panel are consecutive on one XCD.
    const int bid  = blockIdx.x;
    const int cpx  = gridDim.x >> 3;
    const int lid  = (bid & 7) * cpx + (bid >> 3);
    const int mblk = lid / 6;
    const int nblk = lid - mblk * 6;
    const int m0 = mblk << 7;
    const int n0 = nblk << 7;

    const int tid = threadIdx.x;
    const int row = tid >> 1;             // 0..127: A-row (m) and B-row (n)
    const int c0  = (tid & 1) << 4;       // 0 or 16 (bf16 column offset)

    const int gm = m0 + row;
    const long abase = (long)(ids ? ids[gm] : gm) * K;
    const float rstd = stats[2 * gm + 1];
    const float nmr  = -stats[2 * gm] * rstd;      // xn = fma(x, rstd, nmr)
    const long bbase = (long)(n0 + row) * Kpad + c0;

    const int lane = tid & 63;
    const int fr = lane & 15;             // fragment row
    const int fk = lane >> 4;             // k-chunk 0..3
    const int wm = (tid >> 7) & 1;        // wave tile 64x64
    const int wn = (tid >> 6) & 1;

    f32x4 acc[4][4] = {};
    f32x4 av[4];
    u16x8 vbh[2], vbl[2];
    const f32x4 zero4 = {0.f, 0.f, 0.f, 0.f};

    auto gload = [&](int k0) {
        #pragma unroll
        for (int i = 0; i < 4; i++) {
            int k = k0 + c0 + 4 * i;
            av[i] = (k < K) ? *(const f32x4*)(A + abase + k) : zero4;
        }
        const u16* ph = Whi + bbase + k0;
        const u16* pl = Wlo + bbase + k0;
        vbh[0] = *(const u16x8*)(ph);
        vbh[1] = *(const u16x8*)(ph + 8);
        vbl[0] = *(const u16x8*)(pl);
        vbl[1] = *(const u16x8*)(pl + 8);
    };

    auto stage = [&](int k0) {
        u16x8 ah[2], al[2];
        #pragma unroll
        for (int i = 0; i < 4; i++) {
            const bool ok = (k0 + c0 + 4 * i) < K;   // K%4==0 always
            #pragma unroll
            for (int j = 0; j < 4; j++) {
                float xn = ok ? __builtin_fmaf(av[i][j], rstd, nmr) : 0.f;
                unsigned u  = __float_as_uint(xn);
                unsigned hb = u & 0xffff0000u;       // exact bf16-truncation
                float    lo = xn - __uint_as_float(hb);  // exact remainder
                int e = 4 * i + j;
                ah[e >> 3][e & 7] = (u16)(u >> 16);
                al[e >> 3][e & 7] = (u16)(__float_as_uint(lo) >> 16);
            }
        }
        *(u16x8*)&Ah[row][c0]     = ah[0];
        *(u16x8*)&Ah[row][c0 + 8] = ah[1];
        *(u16x8*)&Al[row][c0]     = al[0];
        *(u16x8*)&Al[row][c0 + 8] = al[1];
        *(u16x8*)&Bh[row][c0]     = vbh[0];
        *(u16x8*)&Bh[row][c0 + 8] = vbh[1];
        *(u16x8*)&Bl[row][c0]     = vbl[0];
        *(u16x8*)&Bl[row][c0 + 8] = vbl[1];
    };

    const int arow = wm * 64 + fr;
    const int brow = wn * 64 + fr;
    const int cofs = fk * 8;

    gload(0);
    for (int k0 = 0;;) {
        __syncthreads();                 // previous compute done reading LDS
        stage(k0);
        __syncthreads();                 // LDS ready
        k0 += 32;
        if (k0 < Kpad) gload(k0);        // prefetch in flight during MFMAs

        bf16x8 bhf[4], blf[4];
        #pragma unroll
        for (int fn = 0; fn < 4; fn++) {
            bhf[fn] = *(const bf16x8*)&Bh[brow + fn * 16][cofs];
            blf[fn] = *(const bf16x8*)&Bl[brow + fn * 16][cofs];
        }
        #pragma unroll
        for (int fm = 0; fm < 4; fm++) {
            bf16x8 ahf = *(const bf16x8*)&Ah[arow + fm * 16][cofs];
            bf16x8 alf = *(const bf16x8*)&Al[arow + fm * 16][cofs];
            #pragma unroll
            for (int fn = 0; fn < 4; fn++)
                acc[fm][fn] = __builtin_amdgcn_mfma_f32_16x16x32_bf16(
                    alf, bhf[fn], acc[fm][fn], 0, 0, 0);
            #pragma unroll
            for (int fn = 0; fn < 4; fn++)
                acc[fm][fn] = __builtin_amdgcn_mfma_f32_16x16x32_bf16(
                    ahf, blf[fn], acc[fm][fn], 0, 0, 0);
            #pragma unroll
            for (int fn = 0; fn < 4; fn++)
                acc[fm][fn] = __builtin_amdgcn_mfma_f32_16x16x32_bf16(
                    ahf, bhf[fn], acc[fm][fn], 0, 0, 0);
        }
        if (k0 >= Kpad) break;
    }

    // epilogue: C/D layout col = lane&15, row = (lane>>4)*4 + reg
    #pragma unroll
    for (int fn = 0; fn < 4; fn++) {
        const int col = n0 + wn * 64 + fn * 16 + fr;
        const float b2 = bias2[col];
        #pragma unroll
        for (int fm = 0; fm < 4; fm++) {
            float* yp = Y + (long)(m0 + wm * 64 + fm * 16 + fk * 4) * HH + col;
            #pragma unroll
            for (int r = 0; r < 4; r++)
                yp[(long)r * HH] = fmaxf(acc[fm][fn][r] + b2, 0.f);
        }
    }
}

// ---------------------------------------------------------------------------
// out[r] = LN_F( LN2A(yA[r]) + LN2B(yB[r]) + tte[tt[r]] + pe[r % L] )
// One block per row (256 threads x 3 cols). yB may alias outp (row-local,
// all reads precede writes via the reduction barriers).
__global__ __launch_bounds__(256) void combine_final(
    const float* __restrict__ yA, const float* __restrict__ yB,
    const float* __restrict__ gA, const float* __restrict__ bA,
    const float* __restrict__ gB, const float* __restrict__ bB,
    const float* __restrict__ tte, const int* __restrict__ tt,
    const float* __restrict__ gF, const float* __restrict__ bF,
    float* __restrict__ outp)
{
    const int r = blockIdx.x;
    const int l = r & (LL - 1);
    const int tid = threadIdx.x;
    const float* ya = yA + (long)r * HH;
    const float* yb = yB + (long)r * HH;

    float va[3], vb[3], v[3];
    float s = 0.f, ss = 0.f;
    #pragma unroll
    for (int i = 0; i < 3; i++) {
        int c = tid + 256 * i;
        va[i] = ya[c];
        s += va[i]; ss += va[i] * va[i];
    }
    float2 t = block_reduce2(s, ss);
    float uA = t.x / (float)HH;
    float rA = 1.f / sqrtf(fmaxf(t.y / (float)HH - uA * uA, 0.f) + 1e-12f);

    s = 0.f; ss = 0.f;
    #pragma unroll
    for (int i = 0; i < 3; i++) {
        int c = tid + 256 * i;
        vb[i] = yb[c];
        s += vb[i]; ss += vb[i] * vb[i];
    }
    t = block_reduce2(s, ss);
    float uB = t.x / (float)HH;
    float rB = 1.f / sqrtf(fmaxf(t.y / (float)HH - uB * uB, 0.f) + 1e-12f);

    const float* tterow = tte + (long)tt[r] * HH;
    s = 0.f; ss = 0.f;
    #pragma unroll
    for (int i = 0; i < 3; i++) {
        int c = tid + 256 * i;
        int p = c >> 1;
        float ang = (float)l * expf((float)(2 * p) * PE_C);
        float pe = (c & 1) ? cosf(ang) : sinf(ang);
        v[i] = gA[c] * (va[i] - uA) * rA + bA[c]
             + gB[c] * (vb[i] - uB) * rB + bB[c]
             + tterow[c] + pe;
        s += v[i]; ss += v[i] * v[i];
    }
    t = block_reduce2(s, ss);
    float u  = t.x / (float)HH;
    float rs = 1.f / sqrtf(fmaxf(t.y / (float)HH - u * u, 0.f) + 1e-12f);
    #pragma unroll
    for (int i = 0; i < 3; i++) {
        int c = tid + 256 * i;
        outp[(long)r * HH + c] = gF[c] * (v[i] - u) * rs + bF[c];
    }
}

// ---------------------------------------------------------------------------
extern "C" void kernel_launch(void* const* d_in, const int* in_sizes, int n_in,
                              void* d_out, int out_size, void* d_ws, size_t ws_size,
                              hipStream_t stream)
{
    const int*   ids1   = (const int*)  d_in[0];
    const int*   ids2   = (const int*)  d_in[1];
    const float* video  = (const float*)d_in[2];
    const float* region = (const float*)d_in[3];
    const int*   tt1    = (const int*)  d_in[4];
    const int*   tt2    = (const int*)  d_in[5];
    const float* wemb   = (const float*)d_in[6];
    const float* wemb2  = (const float*)d_in[7];
    const float* tte    = (const float*)d_in[8];
    const float* tte2   = (const float*)d_in[9];

    const float* wfc_ln1w  = (const float*)d_in[10];
    const float* wfc_ln1b  = (const float*)d_in[11];
    const float* wfc_W     = (const float*)d_in[12];
    const float* wfc_b     = (const float*)d_in[13];
    const float* wfc_ln2w  = (const float*)d_in[14];
    const float* wfc_ln2b  = (const float*)d_in[15];

    const float* wfc2_ln1w = (const float*)d_in[16];
    const float* wfc2_ln1b = (const float*)d_in[17];
    const float* wfc2_W    = (const float*)d_in[18];
    const float* wfc2_b    = (const float*)d_in[19];
    const float* wfc2_ln2w = (const float*)d_in[20];
    const float* wfc2_ln2b = (const float*)d_in[21];

    const float* vid_ln1w  = (const float*)d_in[22];
    const float* vid_ln1b  = (const float*)d_in[23];
    const float* vid_W     = (const float*)d_in[24];
    const float* vid_b     = (const float*)d_in[25];
    const float* vid_ln2w  = (const float*)d_in[26];
    const float* vid_ln2b  = (const float*)d_in[27];

    const float* reg_ln1w  = (const float*)d_in[28];
    const float* reg_ln1b  = (const float*)d_in[29];
    const float* reg_W     = (const float*)d_in[30];
    const float* reg_b     = (const float*)d_in[31];
    const float* reg_ln2w  = (const float*)d_in[32];
    const float* reg_ln2b  = (const float*)d_in[33];

    const float* ln_w  = (const float*)d_in[34];
    const float* ln_b  = (const float*)d_in[35];
    const float* ln2_w = (const float*)d_in[36];
    const float* ln2_b = (const float*)d_in[37];

    float* out1 = (float*)d_out;                    // e1: 32768x768
    float* out2 = out1 + (long)RR * HH;             // e2

    // ---- workspace layout (all 16B-aligned) ----
    char* wsb = (char*)d_ws;
    float* stats = (float*)wsb;                         // 2*RR floats   (256 KB)
    float* bias2 = (float*)(wsb + 262144);              // 4*768 floats  (12 KB)
    u16*   P     = (u16*)  (wsb + 274432);              // bf16 planes   (17.7 MB)
    u16* wfc_hi  = P;                 // 768*320
    u16* wfc_lo  = P + 245760;
    u16* wfc2_hi = P + 491520;
    u16* wfc2_lo = P + 737280;
    u16* vid_hi  = P + 983040;        // 768*3072
    u16* vid_lo  = P + 3342336;
    u16* reg_hi  = P + 5701632;       // 768*2048
    u16* reg_lo  = P + 7274496;
    float* yA    = (float*)(wsb + 274432 + 17694720);   // 32768x768 fp32 (96 MB)

    // ---- prepasses: fold LN1 affine into W, split to bf16 hi/lo planes ----
    prep_w<<<768, 256, 0, stream>>>(wfc_W,  wfc_b,  wfc_ln1w,  wfc_ln1b,  300,  320,  wfc_hi,  wfc_lo,  bias2);
    prep_w<<<768, 256, 0, stream>>>(wfc2_W, wfc2_b, wfc2_ln1w, wfc2_ln1b, 300,  320,  wfc2_hi, wfc2_lo, bias2 + 768);
    prep_w<<<768, 256, 0, stream>>>(vid_W,  vid_b,  vid_ln1w,  vid_ln1b,  3072, 3072, vid_hi,  vid_lo,  bias2 + 1536);
    prep_w<<<768, 256, 0, stream>>>(reg_W,  reg_b,  reg_ln1w,  reg_ln1b,  2048, 2048, reg_hi,  reg_lo,  bias2 + 2304);

    dim3 gg(6 * (RR / 128));   // 1536 blocks, XCD-swizzled in-kernel

    // ---- e1 = LN( wfc(word_emb[ids1]) + vid(video) + tte[tt1] + pe ) ----
    row_stats<<<RR, 256, 0, stream>>>(wemb, ids1, 300, stats);
    gemm_mfma<<<gg, 256, 0, stream>>>(wemb, ids1, 300, 320, wfc_hi, wfc_lo,
                                      bias2, stats, yA);
    row_stats<<<RR, 256, 0, stream>>>(video, nullptr, 3072, stats);
    gemm_mfma<<<gg, 256, 0, stream>>>(video, nullptr, 3072, 3072, vid_hi, vid_lo,
                                      bias2 + 1536, stats, out1);
    combine_final<<<RR, 256, 0, stream>>>(yA, out1,
                                          wfc_ln2w, wfc_ln2b, vid_ln2w, vid_ln2b,
                                          tte, tt1, ln_w, ln_b, out1);

    // ---- e2 = LN( wfc2(word_emb2[ids2]) + reg(region) + tte2[tt2] + pe ) ----
    row_stats<<<RR, 256, 0, stream>>>(wemb2, ids2, 300, stats);
    gemm_mfma<<<gg, 256, 0, stream>>>(wemb2, ids2, 300, 320, wfc2_hi, wfc2_lo,
                                      bias2 + 768, stats, yA);
    row_stats<<<RR, 256, 0, stream>>>(region, nullptr, 2048, stats);
    gemm_mfma<<<gg, 256, 0, stream>>>(region, nullptr, 2048, 2048, reg_hi, reg_lo,
                                      bias2 + 2304, stats, out2);
    combine_final<<<RR, 256, 0, stream>>>(yA, out2,
                                          wfc2_ln2w, wfc2_ln2b, reg_ln2w, reg_ln2b,
                                          tte2, tt2, ln2_w, ln2_b, out2);
}